// Round 3
// baseline (236.598 us; speedup 1.0000x reference)
//
#include <hip/hip_runtime.h>

// NMS3D: x (4,2,64,256,256) f32, 3x3x3 neighborhood-max excluding center,
// edge padding == index clamping (exact match, incl. zeroed boundary shell).
//
// R3: 2 output rows per thread (4 row-loads -> 2 outputs; was 3 -> 1),
// 1-deep z prefetch, non-temporal float4 stores (output never re-read),
// DC=8 -> grid 2048 = 8 blocks/CU exact, 32 waves/CU.

constexpr int D_   = 64;
constexpr int H_   = 256;
constexpr int W_   = 256;
constexpr int HW_  = H_ * W_;
constexpr int NVOL = 8;    // B * CH
constexpr int DC   = 8;    // depth slices emitted per block

typedef float vf4 __attribute__((ext_vector_type(4)));

__device__ __forceinline__ float f3(float a, float b, float c) {
    return fmaxf(fmaxf(a, b), c);
}

// c8 = 3x3-in-plane max excluding center; cur = full 3x3 in-plane max
__device__ __forceinline__ void rowmax(const float4 va, const float4 b, int tx,
                                       float4& c8, float4& cur)
{
    float vaL = __shfl_up(va.w, 1);   if (tx == 0)  vaL = va.x;
    float vaR = __shfl_down(va.x, 1); if (tx == 63) vaR = va.w;
    float bL  = __shfl_up(b.w, 1);    if (tx == 0)  bL  = b.x;
    float bR  = __shfl_down(b.x, 1);  if (tx == 63) bR  = b.w;
    float4 hv;
    hv.x = f3(vaL, va.x, va.y);  hv.y = f3(va.x, va.y, va.z);
    hv.z = f3(va.y, va.z, va.w); hv.w = f3(va.z, va.w, vaR);
    float4 nb;
    nb.x = fmaxf(bL, b.y);  nb.y = fmaxf(b.x, b.z);
    nb.z = fmaxf(b.y, b.w); nb.w = fmaxf(b.z, bR);
    c8.x  = fmaxf(hv.x, nb.x); c8.y  = fmaxf(hv.y, nb.y);
    c8.z  = fmaxf(hv.z, nb.z); c8.w  = fmaxf(hv.w, nb.w);
    cur.x = fmaxf(c8.x, b.x);  cur.y = fmaxf(c8.y, b.y);
    cur.z = fmaxf(c8.z, b.z);  cur.w = fmaxf(c8.w, b.w);
}

__device__ __forceinline__ void ntstore(float* p, const float4 v)
{
    union { float4 f; vf4 v; } u; u.f = v;
    __builtin_nontemporal_store(u.v, (vf4*)p);
}

__global__ __launch_bounds__(256, 4)
void nms3d(const float* __restrict__ x, float* __restrict__ out)
{
    const int tx = threadIdx.x;                    // 0..63 -> W via float4
    const int ty = threadIdx.y;                    // 0..3
    const int h0 = (blockIdx.y << 3) + (ty << 1);  // even row
    const int h1 = h0 + 1;                         // odd row
    const int n  = blockIdx.z;
    const int z0 = blockIdx.x * DC;

    const float* __restrict__ base  = x   + (size_t)n * D_ * HW_;
    float* __restrict__       obase = out + (size_t)n * D_ * HW_;

    const int rm = (h0 == 0)      ? 0      : h0 - 1;
    const int rp = (h1 == H_ - 1) ? H_ - 1 : h1 + 1;
    const int c  = tx << 2;

    const float* sp0 = base + (size_t)max(z0 - 1, 0) * HW_;
    float4 A = *(const float4*)(sp0 + rm * W_ + c);
    float4 B = *(const float4*)(sp0 + h0 * W_ + c);
    float4 C = *(const float4*)(sp0 + h1 * W_ + c);
    float4 E = *(const float4*)(sp0 + rp * W_ + c);

    // rolling depth state, per output row
    float4 vm9_pp0 = {0,0,0,0}, vm9_p0 = {0,0,0,0}, cr8_p0 = {0,0,0,0}, vprev0 = {0,0,0,0};
    float4 vm9_pp1 = {0,0,0,0}, vm9_p1 = {0,0,0,0}, cr8_p1 = {0,0,0,0}, vprev1 = {0,0,0,0};

#pragma unroll
    for (int t = 0; t < DC + 2; ++t) {
        const int zi = z0 - 1 + t;

        // prefetch next slice before computing current
        const int zn = min(zi + 1, D_ - 1);
        const float* spn = base + (size_t)zn * HW_;
        const float4 An = *(const float4*)(spn + rm * W_ + c);
        const float4 Bn = *(const float4*)(spn + h0 * W_ + c);
        const float4 Cn = *(const float4*)(spn + h1 * W_ + c);
        const float4 En = *(const float4*)(spn + rp * W_ + c);

        // row h0: vertical fold of rows (h0-1, h0+1) = (A, C), mid = B
        float4 va0;
        va0.x = fmaxf(A.x, C.x); va0.y = fmaxf(A.y, C.y);
        va0.z = fmaxf(A.z, C.z); va0.w = fmaxf(A.w, C.w);
        float4 c80, cur0;
        rowmax(va0, B, tx, c80, cur0);

        // row h1: vertical fold of rows (h1-1, h1+1) = (B, E), mid = C
        float4 va1;
        va1.x = fmaxf(B.x, E.x); va1.y = fmaxf(B.y, E.y);
        va1.z = fmaxf(B.z, E.z); va1.w = fmaxf(B.w, E.w);
        float4 c81, cur1;
        rowmax(va1, C, tx, c81, cur1);

        if (zi > z0) {
            const size_t zoff = (size_t)(zi - 1) * HW_ + c;
            float4 mx, o;
            mx.x = f3(vm9_pp0.x, cr8_p0.x, cur0.x);
            mx.y = f3(vm9_pp0.y, cr8_p0.y, cur0.y);
            mx.z = f3(vm9_pp0.z, cr8_p0.z, cur0.z);
            mx.w = f3(vm9_pp0.w, cr8_p0.w, cur0.w);
            o.x = vprev0.x > mx.x ? vprev0.x : 0.0f;
            o.y = vprev0.y > mx.y ? vprev0.y : 0.0f;
            o.z = vprev0.z > mx.z ? vprev0.z : 0.0f;
            o.w = vprev0.w > mx.w ? vprev0.w : 0.0f;
            ntstore(obase + zoff + (size_t)h0 * W_, o);

            mx.x = f3(vm9_pp1.x, cr8_p1.x, cur1.x);
            mx.y = f3(vm9_pp1.y, cr8_p1.y, cur1.y);
            mx.z = f3(vm9_pp1.z, cr8_p1.z, cur1.z);
            mx.w = f3(vm9_pp1.w, cr8_p1.w, cur1.w);
            o.x = vprev1.x > mx.x ? vprev1.x : 0.0f;
            o.y = vprev1.y > mx.y ? vprev1.y : 0.0f;
            o.z = vprev1.z > mx.z ? vprev1.z : 0.0f;
            o.w = vprev1.w > mx.w ? vprev1.w : 0.0f;
            ntstore(obase + zoff + (size_t)h1 * W_, o);
        }
        vm9_pp0 = vm9_p0; vm9_p0 = cur0; cr8_p0 = c80; vprev0 = B;
        vm9_pp1 = vm9_p1; vm9_p1 = cur1; cr8_p1 = c81; vprev1 = C;
        A = An; B = Bn; C = Cn; E = En;
    }
}

extern "C" void kernel_launch(void* const* d_in, const int* in_sizes, int n_in,
                              void* d_out, int out_size, void* d_ws, size_t ws_size,
                              hipStream_t stream)
{
    const float* x = (const float*)d_in[0];
    float* out = (float*)d_out;
    dim3 block(64, 4, 1);
    dim3 grid(D_ / DC, H_ / 8, NVOL);   // 8 x 32 x 8 = 2048 blocks
    nms3d<<<grid, block, 0, stream>>>(x, out);
}

// Round 4
// 228.088 us; speedup vs baseline: 1.0373x; 1.0373x over previous
//
#include <hip/hip_runtime.h>

// NMS3D: x (4,2,64,256,256) f32, 3x3x3 neighborhood-max excluding center,
// edge padding == index clamping (exact match, incl. zeroed boundary shell).
//
// R4 = R2 structure (1 row/thread, 4 shuffles/iter, normal stores, DC=8,
// 4096 blocks) + 2-deep z prefetch: 6 row-loads in flight per wave, so each
// iteration's compute overlaps TWO outstanding slice-loads (partial vmcnt
// waits instead of a full drain). Attacks the measured latency stall
// (VALUBusy 15-23%, BW 2.5-3 TB/s despite L3-resident input).

constexpr int D_   = 64;
constexpr int H_   = 256;
constexpr int W_   = 256;
constexpr int HW_  = H_ * W_;
constexpr int NVOL = 8;    // B * CH
constexpr int DC   = 8;    // depth slices emitted per block

__device__ __forceinline__ float f3(float a, float b, float c) {
    return fmaxf(fmaxf(a, b), c);
}

__global__ __launch_bounds__(256, 4)
void nms3d(const float* __restrict__ x, float* __restrict__ out)
{
    const int tx = threadIdx.x;             // 0..63 -> covers W via float4
    const int ty = threadIdx.y;             // 0..3
    const int h  = (blockIdx.y << 2) + ty;  // 0..255
    const int n  = blockIdx.z;              // 0..7
    const int z0 = blockIdx.x * DC;

    const float* __restrict__ base  = x   + (size_t)n * D_ * HW_;
    float* __restrict__       obase = out + (size_t)n * D_ * HW_;

    const int r0 = (h == 0)      ? 0      : h - 1;
    const int r2 = (h == H_ - 1) ? H_ - 1 : h + 1;
    const int c  = tx << 2;

    // preload slices z0-1 (clamped) and z0: pipeline depth 2
    const float* spA = base + (size_t)max(z0 - 1, 0) * HW_;
    const float* spB = base + (size_t)z0 * HW_;
    float4 a0 = *(const float4*)(spA + r0 * W_ + c);
    float4 b0 = *(const float4*)(spA + h  * W_ + c);
    float4 d0 = *(const float4*)(spA + r2 * W_ + c);
    float4 a1 = *(const float4*)(spB + r0 * W_ + c);
    float4 b1 = *(const float4*)(spB + h  * W_ + c);
    float4 d1 = *(const float4*)(spB + r2 * W_ + c);

    // rolling depth state
    float4 vm9_pp = {0,0,0,0};  // vmax9[z-2]
    float4 vm9_p  = {0,0,0,0};  // vmax9[z-1]
    float4 cr8_p  = {0,0,0,0};  // cross8[z-1]
    float4 vprev  = {0,0,0,0};  // v[z-1]

#pragma unroll
    for (int t = 0; t < DC + 2; ++t) {
        const int zi = z0 - 1 + t;

        // issue loads for slice zi+2 (2-deep prefetch)
        const int zn = min(zi + 2, D_ - 1);
        const float* spn = base + (size_t)zn * HW_;
        const float4 a2 = *(const float4*)(spn + r0 * W_ + c);
        const float4 b2 = *(const float4*)(spn + h  * W_ + c);
        const float4 d2 = *(const float4*)(spn + r2 * W_ + c);

        // compute on slice zi (regs a0/b0/d0, loaded two iterations ago)
        float4 va;
        va.x = fmaxf(a0.x, d0.x); va.y = fmaxf(a0.y, d0.y);
        va.z = fmaxf(a0.z, d0.z); va.w = fmaxf(a0.w, d0.w);

        float vaL = __shfl_up(va.w, 1);   if (tx == 0)  vaL = va.x;
        float vaR = __shfl_down(va.x, 1); if (tx == 63) vaR = va.w;
        float bL  = __shfl_up(b0.w, 1);   if (tx == 0)  bL  = b0.x;
        float bR  = __shfl_down(b0.x, 1); if (tx == 63) bR  = b0.w;

        float4 hv;
        hv.x = f3(vaL, va.x, va.y);  hv.y = f3(va.x, va.y, va.z);
        hv.z = f3(va.y, va.z, va.w); hv.w = f3(va.z, va.w, vaR);
        float4 nb;
        nb.x = fmaxf(bL, b0.y);  nb.y = fmaxf(b0.x, b0.z);
        nb.z = fmaxf(b0.y, b0.w); nb.w = fmaxf(b0.z, bR);

        float4 c8, cur;                      // cross8[zi], vmax9[zi]
        c8.x  = fmaxf(hv.x, nb.x); c8.y  = fmaxf(hv.y, nb.y);
        c8.z  = fmaxf(hv.z, nb.z); c8.w  = fmaxf(hv.w, nb.w);
        cur.x = fmaxf(c8.x, b0.x); cur.y = fmaxf(c8.y, b0.y);
        cur.z = fmaxf(c8.z, b0.z); cur.w = fmaxf(c8.w, b0.w);

        if (zi > z0) {
            // emit out[zi-1]: max_nc = max(vmax9[zi-2], cross8[zi-1], vmax9[zi])
            float4 mx, o;
            mx.x = f3(vm9_pp.x, cr8_p.x, cur.x);
            mx.y = f3(vm9_pp.y, cr8_p.y, cur.y);
            mx.z = f3(vm9_pp.z, cr8_p.z, cur.z);
            mx.w = f3(vm9_pp.w, cr8_p.w, cur.w);
            o.x = vprev.x > mx.x ? vprev.x : 0.0f;
            o.y = vprev.y > mx.y ? vprev.y : 0.0f;
            o.z = vprev.z > mx.z ? vprev.z : 0.0f;
            o.w = vprev.w > mx.w ? vprev.w : 0.0f;
            *(float4*)(obase + (size_t)(zi - 1) * HW_ + (size_t)h * W_ + c) = o;
        }
        vm9_pp = vm9_p; vm9_p = cur; cr8_p = c8; vprev = b0;
        a0 = a1; b0 = b1; d0 = d1;
        a1 = a2; b1 = b2; d1 = d2;
    }
}

extern "C" void kernel_launch(void* const* d_in, const int* in_sizes, int n_in,
                              void* d_out, int out_size, void* d_ws, size_t ws_size,
                              hipStream_t stream)
{
    const float* x = (const float*)d_in[0];
    float* out = (float*)d_out;
    dim3 block(64, 4, 1);
    dim3 grid(D_ / DC, H_ / 4, NVOL);   // 8 x 64 x 8 = 4096 blocks
    nms3d<<<grid, block, 0, stream>>>(x, out);
}